// Round 6
// baseline (261.324 us; speedup 1.0000x reference)
//
#include <hip/hip_runtime.h>
#include <hip/hip_bf16.h>

#define SEQ 2048
#define DM  1024
#define NH  4
#define HD  256

typedef __attribute__((ext_vector_type(4))) float f32x4;
typedef __attribute__((ext_vector_type(16))) float f32x16;
typedef __attribute__((ext_vector_type(8))) short bf16x8;

__device__ __forceinline__ void gload16(const void* g, void* l) {
  __builtin_amdgcn_global_load_lds(
      (__attribute__((address_space(1))) void*)(unsigned long long)(g),
      (__attribute__((address_space(3))) void*)(l), 16, 0, 0);
}

__device__ __forceinline__ bf16x8 ldg8(const __hip_bfloat16* p) {
  return *reinterpret_cast<const bf16x8*>(p);
}

__device__ __forceinline__ unsigned pack2(float a, float b) {
  __hip_bfloat162 t = __float22bfloat162_rn(make_float2(a, b));
  return *reinterpret_cast<unsigned*>(&t);  // short0=a, short1=b
}

__device__ __forceinline__ short bfbits(float x) {
  __hip_bfloat16 h = __float2bfloat16(x);
  return *reinterpret_cast<short*>(&h);
}

// ---------------- fp32 -> bf16 ----------------
__global__ __launch_bounds__(256) void cvt_f32_bf16(const float* __restrict__ in,
                                                    __hip_bfloat16* __restrict__ out, int n4) {
  int i = blockIdx.x * 256 + threadIdx.x;
  if (i >= n4) return;
  float4 v = reinterpret_cast<const float4*>(in)[i];
  __hip_bfloat162* o2 = reinterpret_cast<__hip_bfloat162*>(out);
  o2[i * 2 + 0] = __float22bfloat162_rn(make_float2(v.x, v.y));
  o2[i * 2 + 1] = __float22bfloat162_rn(make_float2(v.z, v.w));
}

// ---------------- GEMM: C[m,n] = sum_k A[m,k]*B[n,k] (+bias, +resid) ----------------
template <int EPI>
__global__ __launch_bounds__(256, 2) void gemm_bt(
    const __hip_bfloat16* __restrict__ A, const __hip_bfloat16* __restrict__ Bw,
    const float* __restrict__ bias, const float* __restrict__ resid,
    __hip_bfloat16* __restrict__ Cb, float* __restrict__ Cf, int M, int N, int K) {
  __shared__ __hip_bfloat16 ldsA[128 * 32];
  __shared__ __hip_bfloat16 ldsB[128 * 32];
  const int t = threadIdx.x;
  const int w = t >> 6, l = t & 63;
  const int lg = l >> 4, li = l & 15;
  const int m0 = blockIdx.y * 128, n0 = blockIdx.x * 128;
  const int wm = (w >> 1) * 64, wn = (w & 1) * 64;
  const int c1 = t + 256;
  const __hip_bfloat16* gA0 = A + (size_t)(m0 + (t >> 2)) * K + (t & 3) * 8;
  const __hip_bfloat16* gA1 = A + (size_t)(m0 + (c1 >> 2)) * K + (c1 & 3) * 8;
  const __hip_bfloat16* gB0 = Bw + (size_t)(n0 + (t >> 2)) * K + (t & 3) * 8;
  const __hip_bfloat16* gB1 = Bw + (size_t)(n0 + (c1 >> 2)) * K + (c1 & 3) * 8;
  __hip_bfloat16* lA0 = ldsA + t * 8;
  __hip_bfloat16* lA1 = ldsA + c1 * 8;
  __hip_bfloat16* lB0 = ldsB + t * 8;
  __hip_bfloat16* lB1 = ldsB + c1 * 8;
  f32x4 acc[4][4] = {};
  for (int k0 = 0; k0 < K; k0 += 32) {
    gload16(gA0 + k0, lA0);
    gload16(gA1 + k0, lA1);
    gload16(gB0 + k0, lB0);
    gload16(gB1 + k0, lB1);
    __syncthreads();
    bf16x8 af[4], bfr[4];
#pragma unroll
    for (int i = 0; i < 4; i++) af[i] = ldg8(&ldsA[(wm + i * 16 + li) * 32 + lg * 8]);
#pragma unroll
    for (int i = 0; i < 4; i++) bfr[i] = ldg8(&ldsB[(wn + i * 16 + li) * 32 + lg * 8]);
#pragma unroll
    for (int mi = 0; mi < 4; mi++)
#pragma unroll
      for (int ni = 0; ni < 4; ni++)
        acc[mi][ni] = __builtin_amdgcn_mfma_f32_16x16x32_bf16(af[mi], bfr[ni], acc[mi][ni], 0, 0, 0);
    __syncthreads();
  }
#pragma unroll
  for (int ni = 0; ni < 4; ni++) {
    const int col = n0 + wn + ni * 16 + li;
    const float bv = bias[col];
#pragma unroll
    for (int mi = 0; mi < 4; mi++) {
      const int rowb = m0 + wm + mi * 16 + lg * 4;
#pragma unroll
      for (int r = 0; r < 4; r++) {
        const size_t idx = (size_t)(rowb + r) * N + col;
        float v = acc[mi][ni][r] + bv;
        if (EPI) {
          Cf[idx] = v + resid[idx];
        } else {
          Cb[idx] = __float2bfloat16(v);
        }
      }
    }
  }
}

// ---------------- V transpose: vt[bh][d][s] <- qkv[.., 2048 + h*256 + d] ----------------
__global__ __launch_bounds__(256) void transpose_v(const short* __restrict__ qkv,
                                                   short* __restrict__ vt) {
  __shared__ short tile[32][36];
  const int t = threadIdx.x;
  const int bh = blockIdx.z, b = bh >> 2, h = bh & 3;
  const int s0 = blockIdx.x * 32, d0 = blockIdx.y * 32;
  const int sr = t >> 3, c4 = (t & 7) * 4;
  const short* src = qkv + (size_t)(b * SEQ + s0 + sr) * 3072 + 2048 + h * HD + d0 + c4;
  short4 vv = *reinterpret_cast<const short4*>(src);
  tile[sr][c4 + 0] = vv.x;
  tile[sr][c4 + 1] = vv.y;
  tile[sr][c4 + 2] = vv.z;
  tile[sr][c4 + 3] = vv.w;
  __syncthreads();
  short* dst = vt + (size_t)(bh * HD + d0 + sr) * SEQ + s0 + c4;
  short4 ov;
  ov.x = tile[c4 + 0][sr];
  ov.y = tile[c4 + 1][sr];
  ov.z = tile[c4 + 2][sr];
  ov.w = tile[c4 + 3][sr];
  *reinterpret_cast<short4*>(dst) = ov;
}

// ---------------- flash attention v8: v7 core + KVBLK=32 double-buffered prefetch ----------
// v7 (passed): 512-thread blocks = 2 groups x 4 waves; group g owns kv half [g*1024,+1024) for
// the same 128 q rows; 32 q/wave via 32x32 MFMA; S^T = mfma(A=K,B=Q); in-register softmax +
// P-pack (2 shfl_xor(32)); PV: O^T = mfma(A=V^T,B=P^T); cross-group combine through dead LDS.
// v8 change (schedule only): KVBLK 64->32, K/V double-buffered PER GROUP; issue tile t+1's
// global_load_lds into buf^1 BEFORE computing tile t from buf; ONE barrier per iteration
// (r1/r2/r5-proven mechanism). Staging latency (~1.2K cyc) hides under ~3K cyc compute;
// finer granularity lets the 2 waves/SIMD slip phase and overlap DS vs MFMA/VALU.
// r5 counters showed pipes running serially (18.6K cyc/iter vs 15.5K serial sum).
// Swizzles: K rows 512B, chunk ^= (kv&7)  [byte-identical to r0-r5, passed]
//           V rows 64B (32 kv), chunk ^= (d&3)  [2-bit; reads 2-way bank-aliased = free, m136]
// Fragment maps (32x32x16): A row=l&31,k=(l>>5)*8+j; B col=l&31,k=(l>>5)*8+j;
// C col=l&31,row=(r&3)+8*(r>>2)+4*(l>>5)  [verified by r5 pass].
__global__ __launch_bounds__(512, 2) void flash_attn(const __hip_bfloat16* __restrict__ qkv,
                                                     const __hip_bfloat16* __restrict__ vt,
                                                     __hip_bfloat16* __restrict__ attno) {
  __shared__ __hip_bfloat16 ldsK[2][2][32 * 256];  // [group][buf][kv 32][d 256]  64 KB
  __shared__ __hip_bfloat16 ldsV[2][2][256 * 32];  // [group][buf][d 256][kv 32]  64 KB
  __shared__ float mlx[8][2][32];                  // [wave][m,l][q]              2 KB
  const int tid = threadIdx.x, w = tid >> 6, l = tid & 63;
  const int l31 = l & 31, hi = l >> 5;
  const int g = w >> 2, gt = tid & 255;
  const int bid = blockIdx.x;
  const int bh = (bid & 7) * 2 + ((bid >> 3) & 1);  // XCD-affine: 2 bh per XCD
  const int qt = bid >> 4;
  const int b = bh >> 2, h = bh & 3;
  const int qsub = qt * 128 + (w & 3) * 32;
  const int kvbase = g * 1024;
  // Q B-frags: bq[kst] = Q[q=l31][kst*16 + hi*8 + j]
  bf16x8 bq[16];
  {
    const __hip_bfloat16* Qp = qkv + (size_t)(b * SEQ + qsub + l31) * 3072 + h * HD + hi * 8;
#pragma unroll
    for (int kst = 0; kst < 16; kst++) bq[kst] = ldg8(Qp + kst * 16);
  }
  // K staging: round i (i<4) writes rows kv=i*8+(gt>>5); phys chunk gt&31 holds data ^(kv&7)
  const int kcd = (gt & 31) ^ ((gt >> 5) & 7);
  const __hip_bfloat16* Kg =
      qkv + (size_t)(b * SEQ + kvbase + (gt >> 5)) * 3072 + 1024 + h * HD + kcd * 8;
  // V staging: round i (i<4) writes rows d=i*64+(gt>>2); phys chunk gt&3 holds data ^(d&3)
  const int vcd = (gt & 3) ^ ((gt >> 2) & 3);
  const __hip_bfloat16* Vg =
      vt + (size_t)bh * HD * SEQ + (size_t)(gt >> 2) * SEQ + kvbase + vcd * 8;
  __hip_bfloat16* lKb[2] = {&ldsK[g][0][0], &ldsK[g][1][0]};
  __hip_bfloat16* lVb[2] = {&ldsV[g][0][0], &ldsV[g][1][0]};

  f32x16 oacc[8] = {};
  float m_run = -1e30f, lsum = 0.f;

  // prologue: stage tile 0 into buf 0
#pragma unroll
  for (int i = 0; i < 4; i++) gload16(Kg + (size_t)(i * 8) * 3072, lKb[0] + i * 2048 + gt * 8);
#pragma unroll
  for (int i = 0; i < 4; i++) gload16(Vg + (size_t)(i * 64) * SEQ, lVb[0] + i * 2048 + gt * 8);
  __syncthreads();

#pragma unroll 2
  for (int t = 0; t < 32; ++t) {
    const int cur = t & 1;
    // ---- issue next tile's loads first: latency hides under this tile's compute ----
    if (t + 1 < 32) {
      const int nk = (t + 1) * 32;
#pragma unroll
      for (int i = 0; i < 4; i++)
        gload16(Kg + (size_t)(nk + i * 8) * 3072, lKb[cur ^ 1] + i * 2048 + gt * 8);
#pragma unroll
      for (int i = 0; i < 4; i++)
        gload16(Vg + (size_t)(i * 64) * SEQ + nk, lVb[cur ^ 1] + i * 2048 + gt * 8);
    }
    const __hip_bfloat16* lK = lKb[cur];
    const __hip_bfloat16* lV = lVb[cur];
    // ---- S^T[kv32][q]: 16 MFMAs, 2 independent chains ----
    f32x16 sa = {}, sb = {};
    const int ksw = l31 & 7;
#pragma unroll
    for (int kst = 0; kst < 8; kst++) {
      bf16x8 aka = ldg8(&lK[l31 * 256 + (((4 * kst + hi) ^ ksw) << 3)]);
      bf16x8 akb = ldg8(&lK[l31 * 256 + (((4 * kst + 2 + hi) ^ ksw) << 3)]);
      sa = __builtin_amdgcn_mfma_f32_32x32x16_bf16(aka, bq[2 * kst], sa, 0, 0, 0);
      sb = __builtin_amdgcn_mfma_f32_32x32x16_bf16(akb, bq[2 * kst + 1], sb, 0, 0, 0);
    }
#pragma unroll
    for (int r = 0; r < 16; r++) sa[r] = (sa[r] + sb[r]) * 0.0625f;  // hd^-0.5
    // ---- in-register online softmax (lane owns q=l31; partner l^32 has other 16 rows) ----
    float rmax = sa[0];
#pragma unroll
    for (int r = 1; r < 16; r++) rmax = fmaxf(rmax, sa[r]);
    rmax = fmaxf(rmax, __shfl_xor(rmax, 32));
    if (rmax > m_run + 8.f) {  // defer-max THR=8
      const float alpha = __expf(m_run - rmax);
      m_run = rmax;
      lsum *= alpha;
#pragma unroll
      for (int dt = 0; dt < 8; dt++)
#pragma unroll
        for (int r = 0; r < 16; r++) oacc[dt][r] *= alpha;
    }
    float psum = 0.f;
#pragma unroll
    for (int r = 0; r < 16; r++) {
      sa[r] = __expf(sa[r] - m_run);  // bounded by e^8
      psum += sa[r];
    }
    lsum += psum + __shfl_xor(psum, 32);
    // ---- pack P^T into B-frags + PV (2 k-steps of 16 kv) ----
#pragma unroll
    for (int ks = 0; ks < 2; ks++) {
      const int rb = ks * 8;
      // own packs: a* = kv16 (4hi+0..3); b* = kv16 (8+4hi..11+4hi)
      unsigned a0 = pack2(sa[rb + 0], sa[rb + 1]);
      unsigned a1 = pack2(sa[rb + 2], sa[rb + 3]);
      unsigned b0 = pack2(sa[rb + 4], sa[rb + 5]);
      unsigned b1 = pack2(sa[rb + 6], sa[rb + 7]);
      // hi=0 sends b*, receives partner a* (kv16 4-7); hi=1 sends a*, receives b* (kv16 8-11)
      unsigned s0 = (unsigned)__shfl_xor((int)(hi ? a0 : b0), 32);
      unsigned s1 = (unsigned)__shfl_xor((int)(hi ? a1 : b1), 32);
      union { unsigned u[4]; bf16x8 v; } pw;
      pw.u[0] = hi ? s0 : a0;  // k = hi*8 + {0,1}
      pw.u[1] = hi ? s1 : a1;  // k = hi*8 + {2,3}
      pw.u[2] = hi ? b0 : s0;  // k = hi*8 + {4,5}
      pw.u[3] = hi ? b1 : s1;  // k = hi*8 + {6,7}
      // PV: O^T[d][q] += V^T[d][kv] * P^T[kv][q]; A-frag k=hi*8+j -> data chunk ks*2+hi
#pragma unroll
      for (int dt = 0; dt < 8; dt++) {
        const int drow = dt * 32 + l31;
        bf16x8 av = ldg8(&lV[drow * 32 + (((ks * 2 + hi) ^ (drow & 3)) << 3)]);
        oacc[dt] = __builtin_amdgcn_mfma_f32_32x32x16_bf16(av, pw.v, oacc[dt], 0, 0, 0);
      }
    }
    // one barrier per iter: drains in-flight next-tile loads AND guards buffer reuse
    __syncthreads();
  }
  // ---- cross-group flash-combine (through dead K/V LDS; no global partials) ----
  if (l < 32) {
    mlx[w][0][l] = m_run;
    mlx[w][1][l] = lsum;
  }
  __syncthreads();
  {
    const float m_o = mlx[w ^ 4][0][l31];
    const float l_o = mlx[w ^ 4][1][l31];
    const float mm = fmaxf(m_run, m_o);
    const float e_s = __expf(m_run - mm), e_o = __expf(m_o - mm);
    const float wgt = e_s / (e_s * lsum + e_o * l_o);
#pragma unroll
    for (int dt = 0; dt < 8; dt++)
#pragma unroll
      for (int r = 0; r < 16; r++) oacc[dt][r] *= wgt;
  }
  const int pair = w & 3;
  float* xch = pair < 2 ? reinterpret_cast<float*>(&ldsK[0][0][0]) + pair * 8192
                        : reinterpret_cast<float*>(&ldsV[0][0][0]) + (pair - 2) * 8192;
  // exchange layout: float[32 q][256 d], 16B d-chunk swizzled ^ (q&7)
  if (g == 0) {
#pragma unroll
    for (int dt = 0; dt < 8; dt++)
#pragma unroll
      for (int rq = 0; rq < 4; rq++) {
        const int dch = dt * 8 + 2 * rq + hi;
        f32x4 v;
#pragma unroll
        for (int i = 0; i < 4; i++) v[i] = oacc[dt][4 * rq + i];
        *reinterpret_cast<f32x4*>(&xch[l31 * 256 + ((dch ^ (l31 & 7)) << 2)]) = v;
      }
  }
  __syncthreads();
  if (g == 1) {
    const size_t rowb = (size_t)(b * SEQ + qsub + l31) * DM + h * HD;
#pragma unroll
    for (int dt = 0; dt < 8; dt++)
#pragma unroll
      for (int rq = 0; rq < 4; rq++) {
        const int dch = dt * 8 + 2 * rq + hi;
        f32x4 p = *reinterpret_cast<const f32x4*>(&xch[l31 * 256 + ((dch ^ (l31 & 7)) << 2)]);
        short4 sv;
        sv.x = bfbits(p[0] + oacc[dt][4 * rq + 0]);
        sv.y = bfbits(p[1] + oacc[dt][4 * rq + 1]);
        sv.z = bfbits(p[2] + oacc[dt][4 * rq + 2]);
        sv.w = bfbits(p[3] + oacc[dt][4 * rq + 3]);
        *reinterpret_cast<short4*>(
            reinterpret_cast<short*>(attno + rowb + dt * 32 + 8 * rq + 4 * hi)) = sv;
      }
  }
}

// ---------------- LayerNorm: 1 wave per 1024-row ----------------
__global__ __launch_bounds__(256) void layernorm_k(const float* __restrict__ y,
                                                   const float* __restrict__ gamma,
                                                   const float* __restrict__ beta,
                                                   float* __restrict__ out) {
  const int w = threadIdx.x >> 6, l = threadIdx.x & 63;
  const size_t row = (size_t)blockIdx.x * 4 + w;
  const float4* yp = reinterpret_cast<const float4*>(y + row * DM);
  float4 v[4];
  float s = 0.f, s2 = 0.f;
#pragma unroll
  for (int i = 0; i < 4; i++) {
    v[i] = yp[i * 64 + l];
    s += v[i].x + v[i].y + v[i].z + v[i].w;
    s2 += v[i].x * v[i].x + v[i].y * v[i].y + v[i].z * v[i].z + v[i].w * v[i].w;
  }
#pragma unroll
  for (int off = 1; off < 64; off <<= 1) {
    s += __shfl_xor(s, off);
    s2 += __shfl_xor(s2, off);
  }
  const float mu = s * (1.f / 1024.f);
  const float rs = rsqrtf(s2 * (1.f / 1024.f) - mu * mu + 1e-5f);
  const float4* gp = reinterpret_cast<const float4*>(gamma);
  const float4* bp = reinterpret_cast<const float4*>(beta);
  float4* op = reinterpret_cast<float4*>(out + row * DM);
#pragma unroll
  for (int i = 0; i < 4; i++) {
    float4 g = gp[i * 64 + l], bb = bp[i * 64 + l];
    float4 o;
    o.x = (v[i].x - mu) * rs * g.x + bb.x;
    o.y = (v[i].y - mu) * rs * g.y + bb.y;
    o.z = (v[i].z - mu) * rs * g.z + bb.z;
    o.w = (v[i].w - mu) * rs * g.w + bb.w;
    op[i * 64 + l] = o;
  }
}

extern "C" void kernel_launch(void* const* d_in, const int* in_sizes, int n_in,
                              void* d_out, int out_size, void* d_ws, size_t ws_size,
                              hipStream_t stream) {
  const float* x     = (const float*)d_in[0];
  const float* qkv_w = (const float*)d_in[1];
  const float* qkv_b = (const float*)d_in[2];
  const float* wo_w  = (const float*)d_in[3];
  const float* wo_b  = (const float*)d_in[4];
  const float* gamma = (const float*)d_in[5];
  const float* beta  = (const float*)d_in[6];
  float* out = (float*)d_out;
  char* ws = (char*)d_ws;
  // v0 workspace layout (passed 5x): strictly sequential lifetimes, no overlap while live.
  __hip_bfloat16* xbf   = (__hip_bfloat16*)(ws);             // dead after gemm<0>
  __hip_bfloat16* qkvwb = (__hip_bfloat16*)(ws + 16777216);  // dead after gemm<0>
  __hip_bfloat16* wowb  = (__hip_bfloat16*)(ws + 23068672);  // live until gemm<1>
  __hip_bfloat16* qkv   = (__hip_bfloat16*)(ws + 25165824);  // dead after flash
  float*          yb    = (float*)(ws + 25165824);           // gemm<1> out (aliases dead qkv)
  __hip_bfloat16* vt    = (__hip_bfloat16*)(ws + 75497472);  // dead after flash
  __hip_bfloat16* attno = xbf;                               // flash out (aliases dead xbf)

  cvt_f32_bf16<<<8192, 256, 0, stream>>>(x, xbf, 2097152);
  cvt_f32_bf16<<<3072, 256, 0, stream>>>(qkv_w, qkvwb, 786432);
  cvt_f32_bf16<<<1024, 256, 0, stream>>>(wo_w, wowb, 262144);
  gemm_bt<0><<<dim3(24, 64), 256, 0, stream>>>(xbf, qkvwb, qkv_b, nullptr, qkv, nullptr,
                                               8192, 3072, 1024);
  transpose_v<<<dim3(64, 8, 16), 256, 0, stream>>>((const short*)qkv, (short*)vt);
  flash_attn<<<256, 512, 0, stream>>>(qkv, vt, attno);
  gemm_bt<1><<<dim3(8, 64), 256, 0, stream>>>(attno, wowb, wo_b, x, nullptr, yb,
                                              8192, 1024, 1024);
  layernorm_k<<<2048, 256, 0, stream>>>(yb, gamma, beta, out);
}

// Round 7
// 247.223 us; speedup vs baseline: 1.0570x; 1.0570x over previous
//
#include <hip/hip_runtime.h>
#include <hip/hip_bf16.h>

#define SEQ 2048
#define DM  1024
#define NH  4
#define HD  256

typedef __attribute__((ext_vector_type(4))) float f32x4;
typedef __attribute__((ext_vector_type(16))) float f32x16;
typedef __attribute__((ext_vector_type(8))) short bf16x8;

__device__ __forceinline__ void gload16(const void* g, void* l) {
  __builtin_amdgcn_global_load_lds(
      (__attribute__((address_space(1))) void*)(unsigned long long)(g),
      (__attribute__((address_space(3))) void*)(l), 16, 0, 0);
}

__device__ __forceinline__ bf16x8 ldg8(const __hip_bfloat16* p) {
  return *reinterpret_cast<const bf16x8*>(p);
}

__device__ __forceinline__ unsigned pack2(float a, float b) {
  __hip_bfloat162 t = __float22bfloat162_rn(make_float2(a, b));
  return *reinterpret_cast<unsigned*>(&t);  // short0=a, short1=b
}

__device__ __forceinline__ short bfbits(float x) {
  __hip_bfloat16 h = __float2bfloat16(x);
  return *reinterpret_cast<short*>(&h);
}

// ---------------- fp32 -> bf16 ----------------
__global__ __launch_bounds__(256) void cvt_f32_bf16(const float* __restrict__ in,
                                                    __hip_bfloat16* __restrict__ out, int n4) {
  int i = blockIdx.x * 256 + threadIdx.x;
  if (i >= n4) return;
  float4 v = reinterpret_cast<const float4*>(in)[i];
  __hip_bfloat162* o2 = reinterpret_cast<__hip_bfloat162*>(out);
  o2[i * 2 + 0] = __float22bfloat162_rn(make_float2(v.x, v.y));
  o2[i * 2 + 1] = __float22bfloat162_rn(make_float2(v.z, v.w));
}

// ---------------- GEMM: C[m,n] = sum_k A[m,k]*B[n,k] (+bias, +resid) ----------------
template <int EPI>
__global__ __launch_bounds__(256, 2) void gemm_bt(
    const __hip_bfloat16* __restrict__ A, const __hip_bfloat16* __restrict__ Bw,
    const float* __restrict__ bias, const float* __restrict__ resid,
    __hip_bfloat16* __restrict__ Cb, float* __restrict__ Cf, int M, int N, int K) {
  __shared__ __hip_bfloat16 ldsA[128 * 32];
  __shared__ __hip_bfloat16 ldsB[128 * 32];
  const int t = threadIdx.x;
  const int w = t >> 6, l = t & 63;
  const int lg = l >> 4, li = l & 15;
  const int m0 = blockIdx.y * 128, n0 = blockIdx.x * 128;
  const int wm = (w >> 1) * 64, wn = (w & 1) * 64;
  const int c1 = t + 256;
  const __hip_bfloat16* gA0 = A + (size_t)(m0 + (t >> 2)) * K + (t & 3) * 8;
  const __hip_bfloat16* gA1 = A + (size_t)(m0 + (c1 >> 2)) * K + (c1 & 3) * 8;
  const __hip_bfloat16* gB0 = Bw + (size_t)(n0 + (t >> 2)) * K + (t & 3) * 8;
  const __hip_bfloat16* gB1 = Bw + (size_t)(n0 + (c1 >> 2)) * K + (c1 & 3) * 8;
  __hip_bfloat16* lA0 = ldsA + t * 8;
  __hip_bfloat16* lA1 = ldsA + c1 * 8;
  __hip_bfloat16* lB0 = ldsB + t * 8;
  __hip_bfloat16* lB1 = ldsB + c1 * 8;
  f32x4 acc[4][4] = {};
  for (int k0 = 0; k0 < K; k0 += 32) {
    gload16(gA0 + k0, lA0);
    gload16(gA1 + k0, lA1);
    gload16(gB0 + k0, lB0);
    gload16(gB1 + k0, lB1);
    __syncthreads();
    bf16x8 af[4], bfr[4];
#pragma unroll
    for (int i = 0; i < 4; i++) af[i] = ldg8(&ldsA[(wm + i * 16 + li) * 32 + lg * 8]);
#pragma unroll
    for (int i = 0; i < 4; i++) bfr[i] = ldg8(&ldsB[(wn + i * 16 + li) * 32 + lg * 8]);
#pragma unroll
    for (int mi = 0; mi < 4; mi++)
#pragma unroll
      for (int ni = 0; ni < 4; ni++)
        acc[mi][ni] = __builtin_amdgcn_mfma_f32_16x16x32_bf16(af[mi], bfr[ni], acc[mi][ni], 0, 0, 0);
    __syncthreads();
  }
#pragma unroll
  for (int ni = 0; ni < 4; ni++) {
    const int col = n0 + wn + ni * 16 + li;
    const float bv = bias[col];
#pragma unroll
    for (int mi = 0; mi < 4; mi++) {
      const int rowb = m0 + wm + mi * 16 + lg * 4;
#pragma unroll
      for (int r = 0; r < 4; r++) {
        const size_t idx = (size_t)(rowb + r) * N + col;
        float v = acc[mi][ni][r] + bv;
        if (EPI) {
          Cf[idx] = v + resid[idx];
        } else {
          Cb[idx] = __float2bfloat16(v);
        }
      }
    }
  }
}

// ---------------- V transpose: vt[bh][d][s] <- qkv[.., 2048 + h*256 + d] ----------------
__global__ __launch_bounds__(256) void transpose_v(const short* __restrict__ qkv,
                                                   short* __restrict__ vt) {
  __shared__ short tile[32][36];
  const int t = threadIdx.x;
  const int bh = blockIdx.z, b = bh >> 2, h = bh & 3;
  const int s0 = blockIdx.x * 32, d0 = blockIdx.y * 32;
  const int sr = t >> 3, c4 = (t & 7) * 4;
  const short* src = qkv + (size_t)(b * SEQ + s0 + sr) * 3072 + 2048 + h * HD + d0 + c4;
  short4 vv = *reinterpret_cast<const short4*>(src);
  tile[sr][c4 + 0] = vv.x;
  tile[sr][c4 + 1] = vv.y;
  tile[sr][c4 + 2] = vv.z;
  tile[sr][c4 + 3] = vv.w;
  __syncthreads();
  short* dst = vt + (size_t)(bh * HD + d0 + sr) * SEQ + s0 + c4;
  short4 ov;
  ov.x = tile[c4 + 0][sr];
  ov.y = tile[c4 + 1][sr];
  ov.z = tile[c4 + 2][sr];
  ov.w = tile[c4 + 3][sr];
  *reinterpret_cast<short4*>(dst) = ov;
}

// ---------------- flash attention v9: v8 schedule + conflict-free V swizzle + setprio ------
// v8 post-mortem: per-iter conflict cycles identical to v7 but iters doubled -> V's 2-bit
// (d&3) XOR on 64B rows put 32 lanes on 4 four-bank slots (8-way). Fix: XOR with (d>>1)&3 --
// bank base = 16*(d&1) + 4*(c0^((d>>1)&3)) enumerates all 8 slots over d=0..7 -> 4 lanes/slot
// (= v7's spread). Both sides updated (rule #21): stage vcd = (gt&3)^((gt>>3)&3)
// (d = i*64+(gt>>2) => (d>>1)&3 = (gt>>3)&3, round-independent); read chunk ^ ((drow>>1)&3).
// Plus T5: setprio(1) around QK and PV MFMA clusters (attn-proven +4-7%, m191).
// Everything else byte-identical to v8 (passed): 2 groups x 4 waves, in-block kv-split,
// KVBLK=32 double-buffered prefetch, one barrier/iter, in-register softmax, combine via LDS.
__global__ __launch_bounds__(512, 2) void flash_attn(const __hip_bfloat16* __restrict__ qkv,
                                                     const __hip_bfloat16* __restrict__ vt,
                                                     __hip_bfloat16* __restrict__ attno) {
  __shared__ __hip_bfloat16 ldsK[2][2][32 * 256];  // [group][buf][kv 32][d 256]  64 KB
  __shared__ __hip_bfloat16 ldsV[2][2][256 * 32];  // [group][buf][d 256][kv 32]  64 KB
  __shared__ float mlx[8][2][32];                  // [wave][m,l][q]              2 KB
  const int tid = threadIdx.x, w = tid >> 6, l = tid & 63;
  const int l31 = l & 31, hi = l >> 5;
  const int g = w >> 2, gt = tid & 255;
  const int bid = blockIdx.x;
  const int bh = (bid & 7) * 2 + ((bid >> 3) & 1);  // XCD-affine: 2 bh per XCD
  const int qt = bid >> 4;
  const int b = bh >> 2, h = bh & 3;
  const int qsub = qt * 128 + (w & 3) * 32;
  const int kvbase = g * 1024;
  // Q B-frags: bq[kst] = Q[q=l31][kst*16 + hi*8 + j]
  bf16x8 bq[16];
  {
    const __hip_bfloat16* Qp = qkv + (size_t)(b * SEQ + qsub + l31) * 3072 + h * HD + hi * 8;
#pragma unroll
    for (int kst = 0; kst < 16; kst++) bq[kst] = ldg8(Qp + kst * 16);
  }
  // K staging: round i (i<4) writes rows kv=i*8+(gt>>5); phys chunk gt&31 holds data ^(kv&7)
  const int kcd = (gt & 31) ^ ((gt >> 5) & 7);
  const __hip_bfloat16* Kg =
      qkv + (size_t)(b * SEQ + kvbase + (gt >> 5)) * 3072 + 1024 + h * HD + kcd * 8;
  // V staging: round i (i<4) writes rows d=i*64+(gt>>2); phys chunk gt&3 holds data ^((d>>1)&3)
  const int vcd = (gt & 3) ^ ((gt >> 3) & 3);
  const __hip_bfloat16* Vg =
      vt + (size_t)bh * HD * SEQ + (size_t)(gt >> 2) * SEQ + kvbase + vcd * 8;
  __hip_bfloat16* lKb[2] = {&ldsK[g][0][0], &ldsK[g][1][0]};
  __hip_bfloat16* lVb[2] = {&ldsV[g][0][0], &ldsV[g][1][0]};

  f32x16 oacc[8] = {};
  float m_run = -1e30f, lsum = 0.f;

  // prologue: stage tile 0 into buf 0
#pragma unroll
  for (int i = 0; i < 4; i++) gload16(Kg + (size_t)(i * 8) * 3072, lKb[0] + i * 2048 + gt * 8);
#pragma unroll
  for (int i = 0; i < 4; i++) gload16(Vg + (size_t)(i * 64) * SEQ, lVb[0] + i * 2048 + gt * 8);
  __syncthreads();

#pragma unroll 2
  for (int t = 0; t < 32; ++t) {
    const int cur = t & 1;
    // ---- issue next tile's loads first: latency hides under this tile's compute ----
    if (t + 1 < 32) {
      const int nk = (t + 1) * 32;
#pragma unroll
      for (int i = 0; i < 4; i++)
        gload16(Kg + (size_t)(nk + i * 8) * 3072, lKb[cur ^ 1] + i * 2048 + gt * 8);
#pragma unroll
      for (int i = 0; i < 4; i++)
        gload16(Vg + (size_t)(i * 64) * SEQ + nk, lVb[cur ^ 1] + i * 2048 + gt * 8);
    }
    const __hip_bfloat16* lK = lKb[cur];
    const __hip_bfloat16* lV = lVb[cur];
    // ---- S^T[kv32][q]: 16 MFMAs, 2 independent chains ----
    f32x16 sa = {}, sb = {};
    const int ksw = l31 & 7;
    __builtin_amdgcn_s_setprio(1);
#pragma unroll
    for (int kst = 0; kst < 8; kst++) {
      bf16x8 aka = ldg8(&lK[l31 * 256 + (((4 * kst + hi) ^ ksw) << 3)]);
      bf16x8 akb = ldg8(&lK[l31 * 256 + (((4 * kst + 2 + hi) ^ ksw) << 3)]);
      sa = __builtin_amdgcn_mfma_f32_32x32x16_bf16(aka, bq[2 * kst], sa, 0, 0, 0);
      sb = __builtin_amdgcn_mfma_f32_32x32x16_bf16(akb, bq[2 * kst + 1], sb, 0, 0, 0);
    }
    __builtin_amdgcn_s_setprio(0);
#pragma unroll
    for (int r = 0; r < 16; r++) sa[r] = (sa[r] + sb[r]) * 0.0625f;  // hd^-0.5
    // ---- in-register online softmax (lane owns q=l31; partner l^32 has other 16 rows) ----
    float rmax = sa[0];
#pragma unroll
    for (int r = 1; r < 16; r++) rmax = fmaxf(rmax, sa[r]);
    rmax = fmaxf(rmax, __shfl_xor(rmax, 32));
    if (rmax > m_run + 8.f) {  // defer-max THR=8
      const float alpha = __expf(m_run - rmax);
      m_run = rmax;
      lsum *= alpha;
#pragma unroll
      for (int dt = 0; dt < 8; dt++)
#pragma unroll
        for (int r = 0; r < 16; r++) oacc[dt][r] *= alpha;
    }
    float psum = 0.f;
#pragma unroll
    for (int r = 0; r < 16; r++) {
      sa[r] = __expf(sa[r] - m_run);  // bounded by e^8
      psum += sa[r];
    }
    lsum += psum + __shfl_xor(psum, 32);
    // ---- pack P^T into B-frags + PV (2 k-steps of 16 kv) ----
#pragma unroll
    for (int ks = 0; ks < 2; ks++) {
      const int rb = ks * 8;
      // own packs: a* = kv16 (4hi+0..3); b* = kv16 (8+4hi..11+4hi)
      unsigned a0 = pack2(sa[rb + 0], sa[rb + 1]);
      unsigned a1 = pack2(sa[rb + 2], sa[rb + 3]);
      unsigned b0 = pack2(sa[rb + 4], sa[rb + 5]);
      unsigned b1 = pack2(sa[rb + 6], sa[rb + 7]);
      // hi=0 sends b*, receives partner a* (kv16 4-7); hi=1 sends a*, receives b* (kv16 8-11)
      unsigned s0 = (unsigned)__shfl_xor((int)(hi ? a0 : b0), 32);
      unsigned s1 = (unsigned)__shfl_xor((int)(hi ? a1 : b1), 32);
      union { unsigned u[4]; bf16x8 v; } pw;
      pw.u[0] = hi ? s0 : a0;  // k = hi*8 + {0,1}
      pw.u[1] = hi ? s1 : a1;  // k = hi*8 + {2,3}
      pw.u[2] = hi ? b0 : s0;  // k = hi*8 + {4,5}
      pw.u[3] = hi ? b1 : s1;  // k = hi*8 + {6,7}
      // PV: O^T[d][q] += V^T[d][kv] * P^T[kv][q]; A-frag k=hi*8+j -> data chunk ks*2+hi
      __builtin_amdgcn_s_setprio(1);
#pragma unroll
      for (int dt = 0; dt < 8; dt++) {
        const int drow = dt * 32 + l31;
        bf16x8 av = ldg8(&lV[drow * 32 + (((ks * 2 + hi) ^ ((drow >> 1) & 3)) << 3)]);
        oacc[dt] = __builtin_amdgcn_mfma_f32_32x32x16_bf16(av, pw.v, oacc[dt], 0, 0, 0);
      }
      __builtin_amdgcn_s_setprio(0);
    }
    // one barrier per iter: drains in-flight next-tile loads AND guards buffer reuse
    __syncthreads();
  }
  // ---- cross-group flash-combine (through dead K/V LDS; no global partials) ----
  if (l < 32) {
    mlx[w][0][l] = m_run;
    mlx[w][1][l] = lsum;
  }
  __syncthreads();
  {
    const float m_o = mlx[w ^ 4][0][l31];
    const float l_o = mlx[w ^ 4][1][l31];
    const float mm = fmaxf(m_run, m_o);
    const float e_s = __expf(m_run - mm), e_o = __expf(m_o - mm);
    const float wgt = e_s / (e_s * lsum + e_o * l_o);
#pragma unroll
    for (int dt = 0; dt < 8; dt++)
#pragma unroll
      for (int r = 0; r < 16; r++) oacc[dt][r] *= wgt;
  }
  const int pair = w & 3;
  float* xch = pair < 2 ? reinterpret_cast<float*>(&ldsK[0][0][0]) + pair * 8192
                        : reinterpret_cast<float*>(&ldsV[0][0][0]) + (pair - 2) * 8192;
  // exchange layout: float[32 q][256 d], 16B d-chunk swizzled ^ (q&7)
  if (g == 0) {
#pragma unroll
    for (int dt = 0; dt < 8; dt++)
#pragma unroll
      for (int rq = 0; rq < 4; rq++) {
        const int dch = dt * 8 + 2 * rq + hi;
        f32x4 v;
#pragma unroll
        for (int i = 0; i < 4; i++) v[i] = oacc[dt][4 * rq + i];
        *reinterpret_cast<f32x4*>(&xch[l31 * 256 + ((dch ^ (l31 & 7)) << 2)]) = v;
      }
  }
  __syncthreads();
  if (g == 1) {
    const size_t rowb = (size_t)(b * SEQ + qsub + l31) * DM + h * HD;
#pragma unroll
    for (int dt = 0; dt < 8; dt++)
#pragma unroll
      for (int rq = 0; rq < 4; rq++) {
        const int dch = dt * 8 + 2 * rq + hi;
        f32x4 p = *reinterpret_cast<const f32x4*>(&xch[l31 * 256 + ((dch ^ (l31 & 7)) << 2)]);
        short4 sv;
        sv.x = bfbits(p[0] + oacc[dt][4 * rq + 0]);
        sv.y = bfbits(p[1] + oacc[dt][4 * rq + 1]);
        sv.z = bfbits(p[2] + oacc[dt][4 * rq + 2]);
        sv.w = bfbits(p[3] + oacc[dt][4 * rq + 3]);
        *reinterpret_cast<short4*>(
            reinterpret_cast<short*>(attno + rowb + dt * 32 + 8 * rq + 4 * hi)) = sv;
      }
  }
}

// ---------------- LayerNorm: 1 wave per 1024-row ----------------
__global__ __launch_bounds__(256) void layernorm_k(const float* __restrict__ y,
                                                   const float* __restrict__ gamma,
                                                   const float* __restrict__ beta,
                                                   float* __restrict__ out) {
  const int w = threadIdx.x >> 6, l = threadIdx.x & 63;
  const size_t row = (size_t)blockIdx.x * 4 + w;
  const float4* yp = reinterpret_cast<const float4*>(y + row * DM);
  float4 v[4];
  float s = 0.f, s2 = 0.f;
#pragma unroll
  for (int i = 0; i < 4; i++) {
    v[i] = yp[i * 64 + l];
    s += v[i].x + v[i].y + v[i].z + v[i].w;
    s2 += v[i].x * v[i].x + v[i].y * v[i].y + v[i].z * v[i].z + v[i].w * v[i].w;
  }
#pragma unroll
  for (int off = 1; off < 64; off <<= 1) {
    s += __shfl_xor(s, off);
    s2 += __shfl_xor(s2, off);
  }
  const float mu = s * (1.f / 1024.f);
  const float rs = rsqrtf(s2 * (1.f / 1024.f) - mu * mu + 1e-5f);
  const float4* gp = reinterpret_cast<const float4*>(gamma);
  const float4* bp = reinterpret_cast<const float4*>(beta);
  float4* op = reinterpret_cast<float4*>(out + row * DM);
#pragma unroll
  for (int i = 0; i < 4; i++) {
    float4 g = gp[i * 64 + l], bb = bp[i * 64 + l];
    float4 o;
    o.x = (v[i].x - mu) * rs * g.x + bb.x;
    o.y = (v[i].y - mu) * rs * g.y + bb.y;
    o.z = (v[i].z - mu) * rs * g.z + bb.z;
    o.w = (v[i].w - mu) * rs * g.w + bb.w;
    op[i * 64 + l] = o;
  }
}

extern "C" void kernel_launch(void* const* d_in, const int* in_sizes, int n_in,
                              void* d_out, int out_size, void* d_ws, size_t ws_size,
                              hipStream_t stream) {
  const float* x     = (const float*)d_in[0];
  const float* qkv_w = (const float*)d_in[1];
  const float* qkv_b = (const float*)d_in[2];
  const float* wo_w  = (const float*)d_in[3];
  const float* wo_b  = (const float*)d_in[4];
  const float* gamma = (const float*)d_in[5];
  const float* beta  = (const float*)d_in[6];
  float* out = (float*)d_out;
  char* ws = (char*)d_ws;
  // v0 workspace layout (passed 6x): strictly sequential lifetimes, no overlap while live.
  __hip_bfloat16* xbf   = (__hip_bfloat16*)(ws);             // dead after gemm<0>
  __hip_bfloat16* qkvwb = (__hip_bfloat16*)(ws + 16777216);  // dead after gemm<0>
  __hip_bfloat16* wowb  = (__hip_bfloat16*)(ws + 23068672);  // live until gemm<1>
  __hip_bfloat16* qkv   = (__hip_bfloat16*)(ws + 25165824);  // dead after flash
  float*          yb    = (float*)(ws + 25165824);           // gemm<1> out (aliases dead qkv)
  __hip_bfloat16* vt    = (__hip_bfloat16*)(ws + 75497472);  // dead after flash
  __hip_bfloat16* attno = xbf;                               // flash out (aliases dead xbf)

  cvt_f32_bf16<<<8192, 256, 0, stream>>>(x, xbf, 2097152);
  cvt_f32_bf16<<<3072, 256, 0, stream>>>(qkv_w, qkvwb, 786432);
  cvt_f32_bf16<<<1024, 256, 0, stream>>>(wo_w, wowb, 262144);
  gemm_bt<0><<<dim3(24, 64), 256, 0, stream>>>(xbf, qkvwb, qkv_b, nullptr, qkv, nullptr,
                                               8192, 3072, 1024);
  transpose_v<<<dim3(64, 8, 16), 256, 0, stream>>>((const short*)qkv, (short*)vt);
  flash_attn<<<256, 512, 0, stream>>>(qkv, vt, attno);
  gemm_bt<1><<<dim3(8, 64), 256, 0, stream>>>(attno, wowb, wo_b, x, nullptr, yb,
                                              8192, 1024, 1024);
  layernorm_k<<<2048, 256, 0, stream>>>(yb, gamma, beta, out);
}

// Round 8
// 240.084 us; speedup vs baseline: 1.0885x; 1.0297x over previous
//
#include <hip/hip_runtime.h>
#include <hip/hip_bf16.h>

#define SEQ 2048
#define DM  1024
#define NH  4
#define HD  256

typedef __attribute__((ext_vector_type(4))) float f32x4;
typedef __attribute__((ext_vector_type(16))) float f32x16;
typedef __attribute__((ext_vector_type(8))) short bf16x8;

__device__ __forceinline__ void gload16(const void* g, void* l) {
  __builtin_amdgcn_global_load_lds(
      (__attribute__((address_space(1))) void*)(unsigned long long)(g),
      (__attribute__((address_space(3))) void*)(l), 16, 0, 0);
}

__device__ __forceinline__ bf16x8 ldg8(const __hip_bfloat16* p) {
  return *reinterpret_cast<const bf16x8*>(p);
}

__device__ __forceinline__ unsigned pack2(float a, float b) {
  __hip_bfloat162 t = __float22bfloat162_rn(make_float2(a, b));
  return *reinterpret_cast<unsigned*>(&t);  // short0=a, short1=b
}

__device__ __forceinline__ short bfbits(float x) {
  __hip_bfloat16 h = __float2bfloat16(x);
  return *reinterpret_cast<short*>(&h);
}

// ---------------- fp32 -> bf16 (x, qkv_w, wo_w fused: 3 launches -> 1) ----------------
__global__ __launch_bounds__(256) void cvt3(const float* __restrict__ x,
                                            const float* __restrict__ qw,
                                            const float* __restrict__ ww,
                                            __hip_bfloat16* __restrict__ xo,
                                            __hip_bfloat16* __restrict__ qo,
                                            __hip_bfloat16* __restrict__ wo) {
  int i = blockIdx.x * 256 + threadIdx.x;  // grid covers exactly 3145728 float4s
  const float* src;
  __hip_bfloat16* dst;
  int j;
  if (i < 2097152) {
    src = x; dst = xo; j = i;
  } else if (i < 2883584) {
    src = qw; dst = qo; j = i - 2097152;
  } else {
    src = ww; dst = wo; j = i - 2883584;
  }
  float4 v = reinterpret_cast<const float4*>(src)[j];
  __hip_bfloat162* o2 = reinterpret_cast<__hip_bfloat162*>(dst);
  o2[j * 2 + 0] = __float22bfloat162_rn(make_float2(v.x, v.y));
  o2[j * 2 + 1] = __float22bfloat162_rn(make_float2(v.z, v.w));
}

// ---------------- GEMM: C[m,n] = sum_k A[m,k]*B[n,k] (+bias, +resid) ----------------
// v2: counted-vmcnt pipeline (T4), 3-buffer LDS ring, lead-2 prefetch.
// Compute body + staging addresses byte-identical to the 7x-passed m97-structure kernel;
// ONLY the buffering/sync changed, plus a 2-bit XOR chunk swizzle (flash-V-proven form).
// Invariants (per-thread FIFO vmcnt, 4 loads/tile):
//   prologue: STAGE(0),STAGE(1) -> 8 outstanding; vmcnt(4) drains tile0; barrier.
//   iter kt:  STAGE(kt+2) into buf[(kt+2)%3] (holds tile kt-1, dead since last barrier);
//             compute tile kt; vmcnt(4) drains tile kt+1 (keeps kt+2's 4); barrier.
//   tail kt=T-2: no stage; vmcnt(0) (cheap, loads are old). Never vmcnt(0) in steady state.
// Swizzle (rule #21 both-sides): LDS rows 64B = 4 chunks of 16B; phys chunk c at row r holds
// data chunk c ^ ((r>>1)&3); stage source pre-swizzled (t&3)^((t>>3)&3) (round-independent);
// read chunk = lg ^ ((row>>1)&3). 8-lane b128 subgroups -> 8 distinct 4-bank slots (conflict-free).
template <int EPI>
__global__ __launch_bounds__(256, 3) void gemm_bt(
    const __hip_bfloat16* __restrict__ A, const __hip_bfloat16* __restrict__ Bw,
    const float* __restrict__ bias, const float* __restrict__ resid,
    __hip_bfloat16* __restrict__ Cb, float* __restrict__ Cf, int M, int N, int K) {
  __shared__ __hip_bfloat16 lA[3][128 * 32];  // 3 x 8 KB
  __shared__ __hip_bfloat16 lB[3][128 * 32];  // 3 x 8 KB   (48 KB -> 3 blocks/CU)
  const int t = threadIdx.x;
  const int w = t >> 6, l = t & 63;
  const int lg = l >> 4, li = l & 15;
  const int m0 = blockIdx.y * 128, n0 = blockIdx.x * 128;
  const int wm = (w >> 1) * 64, wn = (w & 1) * 64;
  // staging: thread covers rows (t>>2) and 64+(t>>2); pre-swizzled data chunk (same both rows)
  const int ca = (((t & 3) ^ ((t >> 3) & 3))) * 8;
  const __hip_bfloat16* gA0 = A + (size_t)(m0 + (t >> 2)) * K + ca;
  const __hip_bfloat16* gA1 = A + (size_t)(m0 + 64 + (t >> 2)) * K + ca;
  const __hip_bfloat16* gB0 = Bw + (size_t)(n0 + (t >> 2)) * K + ca;
  const __hip_bfloat16* gB1 = Bw + (size_t)(n0 + 64 + (t >> 2)) * K + ca;
  const int loff = t * 8;  // LDS linear dest (wave-uniform base + lane*16B)

  auto STAGE = [&](int kt, int buf) {
    const int k0 = kt * 32;
    gload16(gA0 + k0, &lA[buf][loff]);
    gload16(gA1 + k0, &lA[buf][loff + 2048]);
    gload16(gB0 + k0, &lB[buf][loff]);
    gload16(gB1 + k0, &lB[buf][loff + 2048]);
  };

  f32x4 acc[4][4] = {};
  const int T = K >> 5;
  STAGE(0, 0);
  STAGE(1, 1);
  asm volatile("s_waitcnt vmcnt(4)" ::: "memory");
  __builtin_amdgcn_sched_barrier(0);
  __builtin_amdgcn_s_barrier();
  __builtin_amdgcn_sched_barrier(0);
  int cur = 0, nx2 = 2;
  for (int kt = 0; kt < T; ++kt) {
    if (kt + 2 < T) STAGE(kt + 2, nx2);
    bf16x8 af[4], bfr[4];
#pragma unroll
    for (int i = 0; i < 4; i++) {
      const int row = wm + i * 16 + li;
      af[i] = ldg8(&lA[cur][row * 32 + ((lg ^ ((row >> 1) & 3)) << 3)]);
    }
#pragma unroll
    for (int i = 0; i < 4; i++) {
      const int row = wn + i * 16 + li;
      bfr[i] = ldg8(&lB[cur][row * 32 + ((lg ^ ((row >> 1) & 3)) << 3)]);
    }
    asm volatile("s_waitcnt lgkmcnt(0)" ::: "memory");
    __builtin_amdgcn_sched_barrier(0);
#pragma unroll
    for (int mi = 0; mi < 4; mi++)
#pragma unroll
      for (int ni = 0; ni < 4; ni++)
        acc[mi][ni] = __builtin_amdgcn_mfma_f32_16x16x32_bf16(af[mi], bfr[ni], acc[mi][ni], 0, 0, 0);
    if (kt + 2 < T) {
      asm volatile("s_waitcnt vmcnt(4)" ::: "memory");
    } else {
      asm volatile("s_waitcnt vmcnt(0)" ::: "memory");
    }
    __builtin_amdgcn_sched_barrier(0);
    __builtin_amdgcn_s_barrier();
    __builtin_amdgcn_sched_barrier(0);
    cur = (cur == 2) ? 0 : cur + 1;
    nx2 = (nx2 == 2) ? 0 : nx2 + 1;
  }
#pragma unroll
  for (int ni = 0; ni < 4; ni++) {
    const int col = n0 + wn + ni * 16 + li;
    const float bv = bias[col];
#pragma unroll
    for (int mi = 0; mi < 4; mi++) {
      const int rowb = m0 + wm + mi * 16 + lg * 4;
#pragma unroll
      for (int r = 0; r < 4; r++) {
        const size_t idx = (size_t)(rowb + r) * N + col;
        float v = acc[mi][ni][r] + bv;
        if (EPI) {
          Cf[idx] = v + resid[idx];
        } else {
          Cb[idx] = __float2bfloat16(v);
        }
      }
    }
  }
}

// ---------------- V transpose: vt[bh][d][s] <- qkv[.., 2048 + h*256 + d] ----------------
__global__ __launch_bounds__(256) void transpose_v(const short* __restrict__ qkv,
                                                   short* __restrict__ vt) {
  __shared__ short tile[32][36];
  const int t = threadIdx.x;
  const int bh = blockIdx.z, b = bh >> 2, h = bh & 3;
  const int s0 = blockIdx.x * 32, d0 = blockIdx.y * 32;
  const int sr = t >> 3, c4 = (t & 7) * 4;
  const short* src = qkv + (size_t)(b * SEQ + s0 + sr) * 3072 + 2048 + h * HD + d0 + c4;
  short4 vv = *reinterpret_cast<const short4*>(src);
  tile[sr][c4 + 0] = vv.x;
  tile[sr][c4 + 1] = vv.y;
  tile[sr][c4 + 2] = vv.z;
  tile[sr][c4 + 3] = vv.w;
  __syncthreads();
  short* dst = vt + (size_t)(bh * HD + d0 + sr) * SEQ + s0 + c4;
  short4 ov;
  ov.x = tile[c4 + 0][sr];
  ov.y = tile[c4 + 1][sr];
  ov.z = tile[c4 + 2][sr];
  ov.w = tile[c4 + 3][sr];
  *reinterpret_cast<short4*>(dst) = ov;
}

// ---------------- flash attention v9 (UNCHANGED from round 7, passed 117us) ----------------
__global__ __launch_bounds__(512, 2) void flash_attn(const __hip_bfloat16* __restrict__ qkv,
                                                     const __hip_bfloat16* __restrict__ vt,
                                                     __hip_bfloat16* __restrict__ attno) {
  __shared__ __hip_bfloat16 ldsK[2][2][32 * 256];  // [group][buf][kv 32][d 256]  64 KB
  __shared__ __hip_bfloat16 ldsV[2][2][256 * 32];  // [group][buf][d 256][kv 32]  64 KB
  __shared__ float mlx[8][2][32];                  // [wave][m,l][q]              2 KB
  const int tid = threadIdx.x, w = tid >> 6, l = tid & 63;
  const int l31 = l & 31, hi = l >> 5;
  const int g = w >> 2, gt = tid & 255;
  const int bid = blockIdx.x;
  const int bh = (bid & 7) * 2 + ((bid >> 3) & 1);  // XCD-affine: 2 bh per XCD
  const int qt = bid >> 4;
  const int b = bh >> 2, h = bh & 3;
  const int qsub = qt * 128 + (w & 3) * 32;
  const int kvbase = g * 1024;
  // Q B-frags: bq[kst] = Q[q=l31][kst*16 + hi*8 + j]
  bf16x8 bq[16];
  {
    const __hip_bfloat16* Qp = qkv + (size_t)(b * SEQ + qsub + l31) * 3072 + h * HD + hi * 8;
#pragma unroll
    for (int kst = 0; kst < 16; kst++) bq[kst] = ldg8(Qp + kst * 16);
  }
  // K staging: round i (i<4) writes rows kv=i*8+(gt>>5); phys chunk gt&31 holds data ^(kv&7)
  const int kcd = (gt & 31) ^ ((gt >> 5) & 7);
  const __hip_bfloat16* Kg =
      qkv + (size_t)(b * SEQ + kvbase + (gt >> 5)) * 3072 + 1024 + h * HD + kcd * 8;
  // V staging: round i (i<4) writes rows d=i*64+(gt>>2); phys chunk gt&3 holds data ^((d>>1)&3)
  const int vcd = (gt & 3) ^ ((gt >> 3) & 3);
  const __hip_bfloat16* Vg =
      vt + (size_t)bh * HD * SEQ + (size_t)(gt >> 2) * SEQ + kvbase + vcd * 8;
  __hip_bfloat16* lKb[2] = {&ldsK[g][0][0], &ldsK[g][1][0]};
  __hip_bfloat16* lVb[2] = {&ldsV[g][0][0], &ldsV[g][1][0]};

  f32x16 oacc[8] = {};
  float m_run = -1e30f, lsum = 0.f;

  // prologue: stage tile 0 into buf 0
#pragma unroll
  for (int i = 0; i < 4; i++) gload16(Kg + (size_t)(i * 8) * 3072, lKb[0] + i * 2048 + gt * 8);
#pragma unroll
  for (int i = 0; i < 4; i++) gload16(Vg + (size_t)(i * 64) * SEQ, lVb[0] + i * 2048 + gt * 8);
  __syncthreads();

#pragma unroll 2
  for (int t = 0; t < 32; ++t) {
    const int cur = t & 1;
    // ---- issue next tile's loads first: latency hides under this tile's compute ----
    if (t + 1 < 32) {
      const int nk = (t + 1) * 32;
#pragma unroll
      for (int i = 0; i < 4; i++)
        gload16(Kg + (size_t)(nk + i * 8) * 3072, lKb[cur ^ 1] + i * 2048 + gt * 8);
#pragma unroll
      for (int i = 0; i < 4; i++)
        gload16(Vg + (size_t)(i * 64) * SEQ + nk, lVb[cur ^ 1] + i * 2048 + gt * 8);
    }
    const __hip_bfloat16* lK = lKb[cur];
    const __hip_bfloat16* lV = lVb[cur];
    // ---- S^T[kv32][q]: 16 MFMAs, 2 independent chains ----
    f32x16 sa = {}, sb = {};
    const int ksw = l31 & 7;
    __builtin_amdgcn_s_setprio(1);
#pragma unroll
    for (int kst = 0; kst < 8; kst++) {
      bf16x8 aka = ldg8(&lK[l31 * 256 + (((4 * kst + hi) ^ ksw) << 3)]);
      bf16x8 akb = ldg8(&lK[l31 * 256 + (((4 * kst + 2 + hi) ^ ksw) << 3)]);
      sa = __builtin_amdgcn_mfma_f32_32x32x16_bf16(aka, bq[2 * kst], sa, 0, 0, 0);
      sb = __builtin_amdgcn_mfma_f32_32x32x16_bf16(akb, bq[2 * kst + 1], sb, 0, 0, 0);
    }
    __builtin_amdgcn_s_setprio(0);
#pragma unroll
    for (int r = 0; r < 16; r++) sa[r] = (sa[r] + sb[r]) * 0.0625f;  // hd^-0.5
    // ---- in-register online softmax (lane owns q=l31; partner l^32 has other 16 rows) ----
    float rmax = sa[0];
#pragma unroll
    for (int r = 1; r < 16; r++) rmax = fmaxf(rmax, sa[r]);
    rmax = fmaxf(rmax, __shfl_xor(rmax, 32));
    if (rmax > m_run + 8.f) {  // defer-max THR=8
      const float alpha = __expf(m_run - rmax);
      m_run = rmax;
      lsum *= alpha;
#pragma unroll
      for (int dt = 0; dt < 8; dt++)
#pragma unroll
        for (int r = 0; r < 16; r++) oacc[dt][r] *= alpha;
    }
    float psum = 0.f;
#pragma unroll
    for (int r = 0; r < 16; r++) {
      sa[r] = __expf(sa[r] - m_run);  // bounded by e^8
      psum += sa[r];
    }
    lsum += psum + __shfl_xor(psum, 32);
    // ---- pack P^T into B-frags + PV (2 k-steps of 16 kv) ----
#pragma unroll
    for (int ks = 0; ks < 2; ks++) {
      const int rb = ks * 8;
      // own packs: a* = kv16 (4hi+0..3); b* = kv16 (8+4hi..11+4hi)
      unsigned a0 = pack2(sa[rb + 0], sa[rb + 1]);
      unsigned a1 = pack2(sa[rb + 2], sa[rb + 3]);
      unsigned b0 = pack2(sa[rb + 4], sa[rb + 5]);
      unsigned b1 = pack2(sa[rb + 6], sa[rb + 7]);
      // hi=0 sends b*, receives partner a* (kv16 4-7); hi=1 sends a*, receives b* (kv16 8-11)
      unsigned s0 = (unsigned)__shfl_xor((int)(hi ? a0 : b0), 32);
      unsigned s1 = (unsigned)__shfl_xor((int)(hi ? a1 : b1), 32);
      union { unsigned u[4]; bf16x8 v; } pw;
      pw.u[0] = hi ? s0 : a0;  // k = hi*8 + {0,1}
      pw.u[1] = hi ? s1 : a1;  // k = hi*8 + {2,3}
      pw.u[2] = hi ? b0 : s0;  // k = hi*8 + {4,5}
      pw.u[3] = hi ? b1 : s1;  // k = hi*8 + {6,7}
      // PV: O^T[d][q] += V^T[d][kv] * P^T[kv][q]; A-frag k=hi*8+j -> data chunk ks*2+hi
      __builtin_amdgcn_s_setprio(1);
#pragma unroll
      for (int dt = 0; dt < 8; dt++) {
        const int drow = dt * 32 + l31;
        bf16x8 av = ldg8(&lV[drow * 32 + (((ks * 2 + hi) ^ ((drow >> 1) & 3)) << 3)]);
        oacc[dt] = __builtin_amdgcn_mfma_f32_32x32x16_bf16(av, pw.v, oacc[dt], 0, 0, 0);
      }
      __builtin_amdgcn_s_setprio(0);
    }
    // one barrier per iter: drains in-flight next-tile loads AND guards buffer reuse
    __syncthreads();
  }
  // ---- cross-group flash-combine (through dead K/V LDS; no global partials) ----
  if (l < 32) {
    mlx[w][0][l] = m_run;
    mlx[w][1][l] = lsum;
  }
  __syncthreads();
  {
    const float m_o = mlx[w ^ 4][0][l31];
    const float l_o = mlx[w ^ 4][1][l31];
    const float mm = fmaxf(m_run, m_o);
    const float e_s = __expf(m_run - mm), e_o = __expf(m_o - mm);
    const float wgt = e_s / (e_s * lsum + e_o * l_o);
#pragma unroll
    for (int dt = 0; dt < 8; dt++)
#pragma unroll
      for (int r = 0; r < 16; r++) oacc[dt][r] *= wgt;
  }
  const int pair = w & 3;
  float* xch = pair < 2 ? reinterpret_cast<float*>(&ldsK[0][0][0]) + pair * 8192
                        : reinterpret_cast<float*>(&ldsV[0][0][0]) + (pair - 2) * 8192;
  // exchange layout: float[32 q][256 d], 16B d-chunk swizzled ^ (q&7)
  if (g == 0) {
#pragma unroll
    for (int dt = 0; dt < 8; dt++)
#pragma unroll
      for (int rq = 0; rq < 4; rq++) {
        const int dch = dt * 8 + 2 * rq + hi;
        f32x4 v;
#pragma unroll
        for (int i = 0; i < 4; i++) v[i] = oacc[dt][4 * rq + i];
        *reinterpret_cast<f32x4*>(&xch[l31 * 256 + ((dch ^ (l31 & 7)) << 2)]) = v;
      }
  }
  __syncthreads();
  if (g == 1) {
    const size_t rowb = (size_t)(b * SEQ + qsub + l31) * DM + h * HD;
#pragma unroll
    for (int dt = 0; dt < 8; dt++)
#pragma unroll
      for (int rq = 0; rq < 4; rq++) {
        const int dch = dt * 8 + 2 * rq + hi;
        f32x4 p = *reinterpret_cast<const f32x4*>(&xch[l31 * 256 + ((dch ^ (l31 & 7)) << 2)]);
        short4 sv;
        sv.x = bfbits(p[0] + oacc[dt][4 * rq + 0]);
        sv.y = bfbits(p[1] + oacc[dt][4 * rq + 1]);
        sv.z = bfbits(p[2] + oacc[dt][4 * rq + 2]);
        sv.w = bfbits(p[3] + oacc[dt][4 * rq + 3]);
        *reinterpret_cast<short4*>(
            reinterpret_cast<short*>(attno + rowb + dt * 32 + 8 * rq + 4 * hi)) = sv;
      }
  }
}

// ---------------- LayerNorm: 1 wave per 1024-row ----------------
__global__ __launch_bounds__(256) void layernorm_k(const float* __restrict__ y,
                                                   const float* __restrict__ gamma,
                                                   const float* __restrict__ beta,
                                                   float* __restrict__ out) {
  const int w = threadIdx.x >> 6, l = threadIdx.x & 63;
  const size_t row = (size_t)blockIdx.x * 4 + w;
  const float4* yp = reinterpret_cast<const float4*>(y + row * DM);
  float4 v[4];
  float s = 0.f, s2 = 0.f;
#pragma unroll
  for (int i = 0; i < 4; i++) {
    v[i] = yp[i * 64 + l];
    s += v[i].x + v[i].y + v[i].z + v[i].w;
    s2 += v[i].x * v[i].x + v[i].y * v[i].y + v[i].z * v[i].z + v[i].w * v[i].w;
  }
#pragma unroll
  for (int off = 1; off < 64; off <<= 1) {
    s += __shfl_xor(s, off);
    s2 += __shfl_xor(s2, off);
  }
  const float mu = s * (1.f / 1024.f);
  const float rs = rsqrtf(s2 * (1.f / 1024.f) - mu * mu + 1e-5f);
  const float4* gp = reinterpret_cast<const float4*>(gamma);
  const float4* bp = reinterpret_cast<const float4*>(beta);
  float4* op = reinterpret_cast<float4*>(out + row * DM);
#pragma unroll
  for (int i = 0; i < 4; i++) {
    float4 g = gp[i * 64 + l], bb = bp[i * 64 + l];
    float4 o;
    o.x = (v[i].x - mu) * rs * g.x + bb.x;
    o.y = (v[i].y - mu) * rs * g.y + bb.y;
    o.z = (v[i].z - mu) * rs * g.z + bb.z;
    o.w = (v[i].w - mu) * rs * g.w + bb.w;
    op[i * 64 + l] = o;
  }
}

extern "C" void kernel_launch(void* const* d_in, const int* in_sizes, int n_in,
                              void* d_out, int out_size, void* d_ws, size_t ws_size,
                              hipStream_t stream) {
  const float* x     = (const float*)d_in[0];
  const float* qkv_w = (const float*)d_in[1];
  const float* qkv_b = (const float*)d_in[2];
  const float* wo_w  = (const float*)d_in[3];
  const float* wo_b  = (const float*)d_in[4];
  const float* gamma = (const float*)d_in[5];
  const float* beta  = (const float*)d_in[6];
  float* out = (float*)d_out;
  char* ws = (char*)d_ws;
  // v0 workspace layout (passed 7x): strictly sequential lifetimes, no overlap while live.
  __hip_bfloat16* xbf   = (__hip_bfloat16*)(ws);             // dead after gemm<0>
  __hip_bfloat16* qkvwb = (__hip_bfloat16*)(ws + 16777216);  // dead after gemm<0>
  __hip_bfloat16* wowb  = (__hip_bfloat16*)(ws + 23068672);  // live until gemm<1>
  __hip_bfloat16* qkv   = (__hip_bfloat16*)(ws + 25165824);  // dead after flash
  float*          yb    = (float*)(ws + 25165824);           // gemm<1> out (aliases dead qkv)
  __hip_bfloat16* vt    = (__hip_bfloat16*)(ws + 75497472);  // dead after flash
  __hip_bfloat16* attno = xbf;                               // flash out (aliases dead xbf)

  cvt3<<<12288, 256, 0, stream>>>(x, qkv_w, wo_w, xbf, qkvwb, wowb);
  gemm_bt<0><<<dim3(24, 64), 256, 0, stream>>>(xbf, qkvwb, qkv_b, nullptr, qkv, nullptr,
                                               8192, 3072, 1024);
  transpose_v<<<dim3(64, 8, 16), 256, 0, stream>>>((const short*)qkv, (short*)vt);
  flash_attn<<<256, 512, 0, stream>>>(qkv, vt, attno);
  gemm_bt<1><<<dim3(8, 64), 256, 0, stream>>>(attno, wowb, wo_b, x, nullptr, yb,
                                              8192, 1024, 1024);
  layernorm_k<<<2048, 256, 0, stream>>>(yb, gamma, beta, out);
}

// Round 9
// 230.187 us; speedup vs baseline: 1.1353x; 1.0430x over previous
//
#include <hip/hip_runtime.h>
#include <hip/hip_bf16.h>

#define SEQ 2048
#define DM  1024
#define NH  4
#define HD  256

typedef __attribute__((ext_vector_type(4))) float f32x4;
typedef __attribute__((ext_vector_type(16))) float f32x16;
typedef __attribute__((ext_vector_type(8))) short bf16x8;

__device__ __forceinline__ void gload16(const void* g, void* l) {
  __builtin_amdgcn_global_load_lds(
      (__attribute__((address_space(1))) void*)(unsigned long long)(g),
      (__attribute__((address_space(3))) void*)(l), 16, 0, 0);
}

__device__ __forceinline__ bf16x8 ldg8(const __hip_bfloat16* p) {
  return *reinterpret_cast<const bf16x8*>(p);
}

__device__ __forceinline__ unsigned pack2(float a, float b) {
  __hip_bfloat162 t = __float22bfloat162_rn(make_float2(a, b));
  return *reinterpret_cast<unsigned*>(&t);  // short0=a, short1=b
}

__device__ __forceinline__ short bfbits(float x) {
  __hip_bfloat16 h = __float2bfloat16(x);
  return *reinterpret_cast<short*>(&h);
}

// ---------------- fp32 -> bf16 (x, qkv_w, wo_w fused: 3 launches -> 1) ----------------
__global__ __launch_bounds__(256) void cvt3(const float* __restrict__ x,
                                            const float* __restrict__ qw,
                                            const float* __restrict__ ww,
                                            __hip_bfloat16* __restrict__ xo,
                                            __hip_bfloat16* __restrict__ qo,
                                            __hip_bfloat16* __restrict__ wo) {
  int i = blockIdx.x * 256 + threadIdx.x;  // grid covers exactly 3145728 float4s
  const float* src;
  __hip_bfloat16* dst;
  int j;
  if (i < 2097152) {
    src = x; dst = xo; j = i;
  } else if (i < 2883584) {
    src = qw; dst = qo; j = i - 2097152;
  } else {
    src = ww; dst = wo; j = i - 2883584;
  }
  float4 v = reinterpret_cast<const float4*>(src)[j];
  __hip_bfloat162* o2 = reinterpret_cast<__hip_bfloat162*>(dst);
  o2[j * 2 + 0] = __float22bfloat162_rn(make_float2(v.x, v.y));
  o2[j * 2 + 1] = __float22bfloat162_rn(make_float2(v.z, v.w));
}

// ---------------- GEMM: C[m,n] = sum_k A[m,k]*B[n,k] (+bias, +resid) ----------------
// v3: counted-vmcnt 3-buffer ring (round-8, passed) + V-TRANSPOSE FUSED EPILOGUE.
// For EPI=0 (QKV gemm), columns >= 2048 (the V projection) are written directly in the
// transposed layout vt[(b*4+h)*256+d][s] instead of row-major qkv -- transpose_v kernel
// deleted (its 16.7MB write + 16.7MB read + 16.7MB write becomes one 16.7MB write).
// Derivation: b = m0>>11 uniform per block (128-row tiles don't straddle batch rows);
// V-branch uniform per ni (col tile base & 2048 both multiples of 16); h=(col-2048)>>8
// uniform per ni; d=(col-2048)&255 per-lane; s=(m0&2047)+wm+mi*16+lg*4+r.
// Scattered 2B stores (stride-2048 per lane) but each 128B vt line is completed by one
// block -> L2 write-combines; HBM bytes unchanged.
template <int EPI>
__global__ __launch_bounds__(256, 3) void gemm_bt(
    const __hip_bfloat16* __restrict__ A, const __hip_bfloat16* __restrict__ Bw,
    const float* __restrict__ bias, const float* __restrict__ resid,
    __hip_bfloat16* __restrict__ Cb, float* __restrict__ Cf,
    __hip_bfloat16* __restrict__ vtr, int M, int N, int K) {
  __shared__ __hip_bfloat16 lA[3][128 * 32];  // 3 x 8 KB
  __shared__ __hip_bfloat16 lB[3][128 * 32];  // 3 x 8 KB   (48 KB -> 3 blocks/CU)
  const int t = threadIdx.x;
  const int w = t >> 6, l = t & 63;
  const int lg = l >> 4, li = l & 15;
  const int m0 = blockIdx.y * 128, n0 = blockIdx.x * 128;
  const int wm = (w >> 1) * 64, wn = (w & 1) * 64;
  // staging: thread covers rows (t>>2) and 64+(t>>2); pre-swizzled data chunk (same both rows)
  const int ca = (((t & 3) ^ ((t >> 3) & 3))) * 8;
  const __hip_bfloat16* gA0 = A + (size_t)(m0 + (t >> 2)) * K + ca;
  const __hip_bfloat16* gA1 = A + (size_t)(m0 + 64 + (t >> 2)) * K + ca;
  const __hip_bfloat16* gB0 = Bw + (size_t)(n0 + (t >> 2)) * K + ca;
  const __hip_bfloat16* gB1 = Bw + (size_t)(n0 + 64 + (t >> 2)) * K + ca;
  const int loff = t * 8;  // LDS linear dest (wave-uniform base + lane*16B)

  auto STAGE = [&](int kt, int buf) {
    const int k0 = kt * 32;
    gload16(gA0 + k0, &lA[buf][loff]);
    gload16(gA1 + k0, &lA[buf][loff + 2048]);
    gload16(gB0 + k0, &lB[buf][loff]);
    gload16(gB1 + k0, &lB[buf][loff + 2048]);
  };

  f32x4 acc[4][4] = {};
  const int T = K >> 5;
  STAGE(0, 0);
  STAGE(1, 1);
  asm volatile("s_waitcnt vmcnt(4)" ::: "memory");
  __builtin_amdgcn_sched_barrier(0);
  __builtin_amdgcn_s_barrier();
  __builtin_amdgcn_sched_barrier(0);
  int cur = 0, nx2 = 2;
  for (int kt = 0; kt < T; ++kt) {
    if (kt + 2 < T) STAGE(kt + 2, nx2);
    bf16x8 af[4], bfr[4];
#pragma unroll
    for (int i = 0; i < 4; i++) {
      const int row = wm + i * 16 + li;
      af[i] = ldg8(&lA[cur][row * 32 + ((lg ^ ((row >> 1) & 3)) << 3)]);
    }
#pragma unroll
    for (int i = 0; i < 4; i++) {
      const int row = wn + i * 16 + li;
      bfr[i] = ldg8(&lB[cur][row * 32 + ((lg ^ ((row >> 1) & 3)) << 3)]);
    }
    asm volatile("s_waitcnt lgkmcnt(0)" ::: "memory");
    __builtin_amdgcn_sched_barrier(0);
#pragma unroll
    for (int mi = 0; mi < 4; mi++)
#pragma unroll
      for (int ni = 0; ni < 4; ni++)
        acc[mi][ni] = __builtin_amdgcn_mfma_f32_16x16x32_bf16(af[mi], bfr[ni], acc[mi][ni], 0, 0, 0);
    if (kt + 2 < T) {
      asm volatile("s_waitcnt vmcnt(4)" ::: "memory");
    } else {
      asm volatile("s_waitcnt vmcnt(0)" ::: "memory");
    }
    __builtin_amdgcn_sched_barrier(0);
    __builtin_amdgcn_s_barrier();
    __builtin_amdgcn_sched_barrier(0);
    cur = (cur == 2) ? 0 : cur + 1;
    nx2 = (nx2 == 2) ? 0 : nx2 + 1;
  }
#pragma unroll
  for (int ni = 0; ni < 4; ni++) {
    const int col = n0 + wn + ni * 16 + li;
    const float bv = bias[col];
    if (EPI == 0 && col >= 2048) {
      // V projection -> vt[(b*4+h)*256+d][s], fused transpose
      const int hh = (col - 2048) >> 8;   // uniform per ni
      const int dd = (col - 2048) & 255;  // per-lane
      __hip_bfloat16* vcol =
          vtr + ((size_t)((m0 >> 11) * 4 + hh) * 256 + dd) * 2048 + (m0 & 2047);
#pragma unroll
      for (int mi = 0; mi < 4; mi++) {
        const int off = wm + mi * 16 + lg * 4;
#pragma unroll
        for (int r = 0; r < 4; r++)
          vcol[off + r] = __float2bfloat16(acc[mi][ni][r] + bv);
      }
    } else {
#pragma unroll
      for (int mi = 0; mi < 4; mi++) {
        const int rowb = m0 + wm + mi * 16 + lg * 4;
#pragma unroll
        for (int r = 0; r < 4; r++) {
          const size_t idx = (size_t)(rowb + r) * N + col;
          float v = acc[mi][ni][r] + bv;
          if (EPI) {
            Cf[idx] = v + resid[idx];
          } else {
            Cb[idx] = __float2bfloat16(v);
          }
        }
      }
    }
  }
}

// ---------------- flash attention v9 (UNCHANGED from round 7/8, passed 117us) ----------------
__global__ __launch_bounds__(512, 2) void flash_attn(const __hip_bfloat16* __restrict__ qkv,
                                                     const __hip_bfloat16* __restrict__ vt,
                                                     __hip_bfloat16* __restrict__ attno) {
  __shared__ __hip_bfloat16 ldsK[2][2][32 * 256];  // [group][buf][kv 32][d 256]  64 KB
  __shared__ __hip_bfloat16 ldsV[2][2][256 * 32];  // [group][buf][d 256][kv 32]  64 KB
  __shared__ float mlx[8][2][32];                  // [wave][m,l][q]              2 KB
  const int tid = threadIdx.x, w = tid >> 6, l = tid & 63;
  const int l31 = l & 31, hi = l >> 5;
  const int g = w >> 2, gt = tid & 255;
  const int bid = blockIdx.x;
  const int bh = (bid & 7) * 2 + ((bid >> 3) & 1);  // XCD-affine: 2 bh per XCD
  const int qt = bid >> 4;
  const int b = bh >> 2, h = bh & 3;
  const int qsub = qt * 128 + (w & 3) * 32;
  const int kvbase = g * 1024;
  // Q B-frags: bq[kst] = Q[q=l31][kst*16 + hi*8 + j]
  bf16x8 bq[16];
  {
    const __hip_bfloat16* Qp = qkv + (size_t)(b * SEQ + qsub + l31) * 3072 + h * HD + hi * 8;
#pragma unroll
    for (int kst = 0; kst < 16; kst++) bq[kst] = ldg8(Qp + kst * 16);
  }
  // K staging: round i (i<4) writes rows kv=i*8+(gt>>5); phys chunk gt&31 holds data ^(kv&7)
  const int kcd = (gt & 31) ^ ((gt >> 5) & 7);
  const __hip_bfloat16* Kg =
      qkv + (size_t)(b * SEQ + kvbase + (gt >> 5)) * 3072 + 1024 + h * HD + kcd * 8;
  // V staging: round i (i<4) writes rows d=i*64+(gt>>2); phys chunk gt&3 holds data ^((d>>1)&3)
  const int vcd = (gt & 3) ^ ((gt >> 3) & 3);
  const __hip_bfloat16* Vg =
      vt + (size_t)bh * HD * SEQ + (size_t)(gt >> 2) * SEQ + kvbase + vcd * 8;
  __hip_bfloat16* lKb[2] = {&ldsK[g][0][0], &ldsK[g][1][0]};
  __hip_bfloat16* lVb[2] = {&ldsV[g][0][0], &ldsV[g][1][0]};

  f32x16 oacc[8] = {};
  float m_run = -1e30f, lsum = 0.f;

  // prologue: stage tile 0 into buf 0
#pragma unroll
  for (int i = 0; i < 4; i++) gload16(Kg + (size_t)(i * 8) * 3072, lKb[0] + i * 2048 + gt * 8);
#pragma unroll
  for (int i = 0; i < 4; i++) gload16(Vg + (size_t)(i * 64) * SEQ, lVb[0] + i * 2048 + gt * 8);
  __syncthreads();

#pragma unroll 2
  for (int t = 0; t < 32; ++t) {
    const int cur = t & 1;
    // ---- issue next tile's loads first: latency hides under this tile's compute ----
    if (t + 1 < 32) {
      const int nk = (t + 1) * 32;
#pragma unroll
      for (int i = 0; i < 4; i++)
        gload16(Kg + (size_t)(nk + i * 8) * 3072, lKb[cur ^ 1] + i * 2048 + gt * 8);
#pragma unroll
      for (int i = 0; i < 4; i++)
        gload16(Vg + (size_t)(i * 64) * SEQ + nk, lVb[cur ^ 1] + i * 2048 + gt * 8);
    }
    const __hip_bfloat16* lK = lKb[cur];
    const __hip_bfloat16* lV = lVb[cur];
    // ---- S^T[kv32][q]: 16 MFMAs, 2 independent chains ----
    f32x16 sa = {}, sb = {};
    const int ksw = l31 & 7;
    __builtin_amdgcn_s_setprio(1);
#pragma unroll
    for (int kst = 0; kst < 8; kst++) {
      bf16x8 aka = ldg8(&lK[l31 * 256 + (((4 * kst + hi) ^ ksw) << 3)]);
      bf16x8 akb = ldg8(&lK[l31 * 256 + (((4 * kst + 2 + hi) ^ ksw) << 3)]);
      sa = __builtin_amdgcn_mfma_f32_32x32x16_bf16(aka, bq[2 * kst], sa, 0, 0, 0);
      sb = __builtin_amdgcn_mfma_f32_32x32x16_bf16(akb, bq[2 * kst + 1], sb, 0, 0, 0);
    }
    __builtin_amdgcn_s_setprio(0);
#pragma unroll
    for (int r = 0; r < 16; r++) sa[r] = (sa[r] + sb[r]) * 0.0625f;  // hd^-0.5
    // ---- in-register online softmax (lane owns q=l31; partner l^32 has other 16 rows) ----
    float rmax = sa[0];
#pragma unroll
    for (int r = 1; r < 16; r++) rmax = fmaxf(rmax, sa[r]);
    rmax = fmaxf(rmax, __shfl_xor(rmax, 32));
    if (rmax > m_run + 8.f) {  // defer-max THR=8
      const float alpha = __expf(m_run - rmax);
      m_run = rmax;
      lsum *= alpha;
#pragma unroll
      for (int dt = 0; dt < 8; dt++)
#pragma unroll
        for (int r = 0; r < 16; r++) oacc[dt][r] *= alpha;
    }
    float psum = 0.f;
#pragma unroll
    for (int r = 0; r < 16; r++) {
      sa[r] = __expf(sa[r] - m_run);  // bounded by e^8
      psum += sa[r];
    }
    lsum += psum + __shfl_xor(psum, 32);
    // ---- pack P^T into B-frags + PV (2 k-steps of 16 kv) ----
#pragma unroll
    for (int ks = 0; ks < 2; ks++) {
      const int rb = ks * 8;
      // own packs: a* = kv16 (4hi+0..3); b* = kv16 (8+4hi..11+4hi)
      unsigned a0 = pack2(sa[rb + 0], sa[rb + 1]);
      unsigned a1 = pack2(sa[rb + 2], sa[rb + 3]);
      unsigned b0 = pack2(sa[rb + 4], sa[rb + 5]);
      unsigned b1 = pack2(sa[rb + 6], sa[rb + 7]);
      // hi=0 sends b*, receives partner a* (kv16 4-7); hi=1 sends a*, receives b* (kv16 8-11)
      unsigned s0 = (unsigned)__shfl_xor((int)(hi ? a0 : b0), 32);
      unsigned s1 = (unsigned)__shfl_xor((int)(hi ? a1 : b1), 32);
      union { unsigned u[4]; bf16x8 v; } pw;
      pw.u[0] = hi ? s0 : a0;  // k = hi*8 + {0,1}
      pw.u[1] = hi ? s1 : a1;  // k = hi*8 + {2,3}
      pw.u[2] = hi ? b0 : s0;  // k = hi*8 + {4,5}
      pw.u[3] = hi ? b1 : s1;  // k = hi*8 + {6,7}
      // PV: O^T[d][q] += V^T[d][kv] * P^T[kv][q]; A-frag k=hi*8+j -> data chunk ks*2+hi
      __builtin_amdgcn_s_setprio(1);
#pragma unroll
      for (int dt = 0; dt < 8; dt++) {
        const int drow = dt * 32 + l31;
        bf16x8 av = ldg8(&lV[drow * 32 + (((ks * 2 + hi) ^ ((drow >> 1) & 3)) << 3)]);
        oacc[dt] = __builtin_amdgcn_mfma_f32_32x32x16_bf16(av, pw.v, oacc[dt], 0, 0, 0);
      }
      __builtin_amdgcn_s_setprio(0);
    }
    // one barrier per iter: drains in-flight next-tile loads AND guards buffer reuse
    __syncthreads();
  }
  // ---- cross-group flash-combine (through dead K/V LDS; no global partials) ----
  if (l < 32) {
    mlx[w][0][l] = m_run;
    mlx[w][1][l] = lsum;
  }
  __syncthreads();
  {
    const float m_o = mlx[w ^ 4][0][l31];
    const float l_o = mlx[w ^ 4][1][l31];
    const float mm = fmaxf(m_run, m_o);
    const float e_s = __expf(m_run - mm), e_o = __expf(m_o - mm);
    const float wgt = e_s / (e_s * lsum + e_o * l_o);
#pragma unroll
    for (int dt = 0; dt < 8; dt++)
#pragma unroll
      for (int r = 0; r < 16; r++) oacc[dt][r] *= wgt;
  }
  const int pair = w & 3;
  float* xch = pair < 2 ? reinterpret_cast<float*>(&ldsK[0][0][0]) + pair * 8192
                        : reinterpret_cast<float*>(&ldsV[0][0][0]) + (pair - 2) * 8192;
  // exchange layout: float[32 q][256 d], 16B d-chunk swizzled ^ (q&7)
  if (g == 0) {
#pragma unroll
    for (int dt = 0; dt < 8; dt++)
#pragma unroll
      for (int rq = 0; rq < 4; rq++) {
        const int dch = dt * 8 + 2 * rq + hi;
        f32x4 v;
#pragma unroll
        for (int i = 0; i < 4; i++) v[i] = oacc[dt][4 * rq + i];
        *reinterpret_cast<f32x4*>(&xch[l31 * 256 + ((dch ^ (l31 & 7)) << 2)]) = v;
      }
  }
  __syncthreads();
  if (g == 1) {
    const size_t rowb = (size_t)(b * SEQ + qsub + l31) * DM + h * HD;
#pragma unroll
    for (int dt = 0; dt < 8; dt++)
#pragma unroll
      for (int rq = 0; rq < 4; rq++) {
        const int dch = dt * 8 + 2 * rq + hi;
        f32x4 p = *reinterpret_cast<const f32x4*>(&xch[l31 * 256 + ((dch ^ (l31 & 7)) << 2)]);
        short4 sv;
        sv.x = bfbits(p[0] + oacc[dt][4 * rq + 0]);
        sv.y = bfbits(p[1] + oacc[dt][4 * rq + 1]);
        sv.z = bfbits(p[2] + oacc[dt][4 * rq + 2]);
        sv.w = bfbits(p[3] + oacc[dt][4 * rq + 3]);
        *reinterpret_cast<short4*>(
            reinterpret_cast<short*>(attno + rowb + dt * 32 + 8 * rq + 4 * hi)) = sv;
      }
  }
}

// ---------------- LayerNorm: 1 wave per 1024-row ----------------
__global__ __launch_bounds__(256) void layernorm_k(const float* __restrict__ y,
                                                   const float* __restrict__ gamma,
                                                   const float* __restrict__ beta,
                                                   float* __restrict__ out) {
  const int w = threadIdx.x >> 6, l = threadIdx.x & 63;
  const size_t row = (size_t)blockIdx.x * 4 + w;
  const float4* yp = reinterpret_cast<const float4*>(y + row * DM);
  float4 v[4];
  float s = 0.f, s2 = 0.f;
#pragma unroll
  for (int i = 0; i < 4; i++) {
    v[i] = yp[i * 64 + l];
    s += v[i].x + v[i].y + v[i].z + v[i].w;
    s2 += v[i].x * v[i].x + v[i].y * v[i].y + v[i].z * v[i].z + v[i].w * v[i].w;
  }
#pragma unroll
  for (int off = 1; off < 64; off <<= 1) {
    s += __shfl_xor(s, off);
    s2 += __shfl_xor(s2, off);
  }
  const float mu = s * (1.f / 1024.f);
  const float rs = rsqrtf(s2 * (1.f / 1024.f) - mu * mu + 1e-5f);
  const float4* gp = reinterpret_cast<const float4*>(gamma);
  const float4* bp = reinterpret_cast<const float4*>(beta);
  float4* op = reinterpret_cast<float4*>(out + row * DM);
#pragma unroll
  for (int i = 0; i < 4; i++) {
    float4 g = gp[i * 64 + l], bb = bp[i * 64 + l];
    float4 o;
    o.x = (v[i].x - mu) * rs * g.x + bb.x;
    o.y = (v[i].y - mu) * rs * g.y + bb.y;
    o.z = (v[i].z - mu) * rs * g.z + bb.z;
    o.w = (v[i].w - mu) * rs * g.w + bb.w;
    op[i * 64 + l] = o;
  }
}

extern "C" void kernel_launch(void* const* d_in, const int* in_sizes, int n_in,
                              void* d_out, int out_size, void* d_ws, size_t ws_size,
                              hipStream_t stream) {
  const float* x     = (const float*)d_in[0];
  const float* qkv_w = (const float*)d_in[1];
  const float* qkv_b = (const float*)d_in[2];
  const float* wo_w  = (const float*)d_in[3];
  const float* wo_b  = (const float*)d_in[4];
  const float* gamma = (const float*)d_in[5];
  const float* beta  = (const float*)d_in[6];
  float* out = (float*)d_out;
  char* ws = (char*)d_ws;
  // v0 workspace layout (passed 8x): strictly sequential lifetimes, no overlap while live.
  __hip_bfloat16* xbf   = (__hip_bfloat16*)(ws);             // dead after gemm<0>
  __hip_bfloat16* qkvwb = (__hip_bfloat16*)(ws + 16777216);  // dead after gemm<0>
  __hip_bfloat16* wowb  = (__hip_bfloat16*)(ws + 23068672);  // live until gemm<1>
  __hip_bfloat16* qkv   = (__hip_bfloat16*)(ws + 25165824);  // dead after flash
  float*          yb    = (float*)(ws + 25165824);           // gemm<1> out (aliases dead qkv)
  __hip_bfloat16* vt    = (__hip_bfloat16*)(ws + 75497472);  // dead after flash
  __hip_bfloat16* attno = xbf;                               // flash out (aliases dead xbf)

  cvt3<<<12288, 256, 0, stream>>>(x, qkv_w, wo_w, xbf, qkvwb, wowb);
  gemm_bt<0><<<dim3(24, 64), 256, 0, stream>>>(xbf, qkvwb, qkv_b, nullptr, qkv, nullptr,
                                               vt, 8192, 3072, 1024);
  flash_attn<<<256, 512, 0, stream>>>(qkv, vt, attno);
  gemm_bt<1><<<dim3(8, 64), 256, 0, stream>>>(attno, wowb, wo_b, x, nullptr, yb,
                                              nullptr, 8192, 1024, 1024);
  layernorm_k<<<2048, 256, 0, stream>>>(yb, gamma, beta, out);
}